// Round 2
// baseline (287.873 us; speedup 1.0000x reference)
//
#include <hip/hip_runtime.h>
#include <math.h>

#define NQ 4
#define NL 2

typedef __attribute__((ext_vector_type(8))) short short8v;  // 8 x bf16 (4 VGPRs)
typedef __attribute__((ext_vector_type(4))) float f32x4;

__device__ inline unsigned short f2bf(float x){
    unsigned u = __float_as_uint(x);
    u += 0x7FFFu + ((u >> 16) & 1u);          // RNE
    return (unsigned short)(u >> 16);
}
__device__ inline float bf2f(unsigned short h){
    return __uint_as_float(((unsigned)h) << 16);
}
// split x into hi (bf16) + lo (bf16 of residual); 3-term MFMA product keeps ~fp32 accuracy
__device__ inline void split8(const float* x, short8v& hi, short8v& lo){
    #pragma unroll
    for (int e = 0; e < 8; ++e){
        unsigned short h = f2bf(x[e]);
        hi[e] = (short)h;
        lo[e] = (short)f2bf(x[e] - bf2f(h));
    }
}

// ---------------------------------------------------------------------------
// Kernel 1: precompute A = Re(M^dagger D M)  (unchanged)
// ---------------------------------------------------------------------------
__global__ void qnn_precompute_A(const float* __restrict__ qw, float* __restrict__ A)
{
    __shared__ float Mre[16][16];
    __shared__ float Mim[16][16];
    int t = threadIdx.x;
    if (t < 16) {
        int j = t;
        float re[16], im[16];
        for (int b = 0; b < 16; ++b) { re[b] = (b == j) ? 1.f : 0.f; im[b] = 0.f; }
        for (int l = 0; l < NL; ++l) {
            for (int i = 0; i < NQ; ++i) {
                float phi   = qw[(l*NQ + i)*3 + 0];
                float theta = qw[(l*NQ + i)*3 + 1];
                float omega = qw[(l*NQ + i)*3 + 2];
                float ct, st; sincosf(0.5f*theta, &st, &ct);
                float ap = 0.5f*(phi + omega);
                float am = 0.5f*(phi - omega);
                float cap, sap, cam, sam;
                sincosf(ap, &sap, &cap);
                sincosf(am, &sam, &cam);
                float u00r =  cap*ct, u00i = -sap*ct;
                float u01r = -cam*st, u01i = -sam*st;
                float u10r =  cam*st, u10i = -sam*st;
                float u11r =  cap*ct, u11i =  sap*ct;
                int mask = 1 << (3 - i);
                for (int b = 0; b < 16; ++b) {
                    if (b & mask) continue;
                    int b1 = b | mask;
                    float a0r = re[b],  a0i = im[b];
                    float a1r = re[b1], a1i = im[b1];
                    re[b]  = u00r*a0r - u00i*a0i + u01r*a1r - u01i*a1i;
                    im[b]  = u00r*a0i + u00i*a0r + u01r*a1i + u01i*a1r;
                    re[b1] = u10r*a0r - u10i*a0i + u11r*a1r - u11i*a1i;
                    im[b1] = u10r*a0i + u10i*a0r + u11r*a1i + u11i*a1r;
                }
            }
            for (int b = 0; b < 16; ++b) {
                float sgn = 1.f;
                if ((b & 0xC) == 0xC) sgn = -sgn;
                if ((b & 0x6) == 0x6) sgn = -sgn;
                if ((b & 0x3) == 0x3) sgn = -sgn;
                re[b] *= sgn; im[b] *= sgn;
            }
        }
        for (int b = 0; b < 16; ++b) { Mre[j][b] = re[b]; Mim[j][b] = im[b]; }
    }
    __syncthreads();
    {
        int j = t >> 4, k = t & 15;
        float s = 0.f;
        #pragma unroll
        for (int b = 0; b < 16; ++b) {
            float sg = (b & 8) ? -1.f : 1.f;
            s += sg * (Mre[j][b]*Mre[k][b] + Mim[j][b]*Mim[k][b]);
        }
        A[j*16 + k] = s;
    }
}

// ---------------------------------------------------------------------------
// Kernel 2, restructured around MFMA.
// Diagnosis: rounds 0/1 ran at identical 114-115us across 43%->76% occupancy
// with VALUBusy pinned at 35% -> bound by the per-wave s_load weight stream
// (~17KB/wave x 8192 waves = 139MB through the scalar cache). Fix: weights
// live in bf16 MFMA B-fragments loaded ONCE per wave via vector loads.
// Layer-1 GEMMs use mfma_f32_16x16x32_bf16 with 3-term bf16 split
// (hi*hi + hi*lo + lo*hi) for ~fp32 accuracy. The (laneGroup,elem)->k slot
// map is chosen identically for A and B staging, so the HW's internal k
// permutation cancels; only the m89-verified C/D layout
// (row = 4*(lane>>4)+reg, col = lane&15) is relied upon.
// Phase 1 (per wave: 64 samples = 4 M-tiles of 16):
//   A-frags from per-lane global loads + split; 30 MFMA per M-tile;
//   layer-2 (64->4 / 32->4) per-lane on C-frags; shfl_xor reduce over the
//   16-lane N dimension; feats -> 4KB LDS.
// Phase 2: one thread per sample, quantum quadratic form + head (unchanged).
// ---------------------------------------------------------------------------
__global__ __launch_bounds__(256, 3) void qnn_main(
    const float* __restrict__ text, const float* __restrict__ image,
    const float* __restrict__ tW1, const float* __restrict__ tb1,
    const float* __restrict__ tW2, const float* __restrict__ tb2,
    const float* __restrict__ iW1, const float* __restrict__ ib1,
    const float* __restrict__ iW2, const float* __restrict__ ib2,
    const float* __restrict__ A,
    const float* __restrict__ cW1, const float* __restrict__ cb1,
    const float* __restrict__ cW2, const float* __restrict__ cb2,
    float* __restrict__ out, int B)
{
    __shared__ float4 feats[256];
    const int t    = threadIdx.x;
    const int lane = t & 63;
    const int wv   = t >> 6;
    const int g    = lane >> 4;   // k-slot group
    const int c    = lane & 15;   // A row (sample) / B col (neuron) / D col
    const long long blockBase = (long long)blockIdx.x * 256;

    // ---------------- Phase 1: weight fragments (once per wave) -------------
    // k-slot map (shared by A and B): k = ks*32 + 8*g + e
    short8v Bih[4][2], Bil[4][2];                 // image W1: 64 neurons = 4 n-tiles, K=48 -> 2 k-steps
    #pragma unroll
    for (int nt = 0; nt < 4; ++nt)
        #pragma unroll
        for (int ks = 0; ks < 2; ++ks){
            float x[8];
            #pragma unroll
            for (int e = 0; e < 8; ++e){
                int k = ks*32 + 8*g + e;
                x[e] = (k < 48) ? iW1[k*64 + nt*16 + c] : 0.f;
            }
            split8(x, Bih[nt][ks], Bil[nt][ks]);
        }
    short8v Bth[2], Btl[2];                       // text W1: 32 neurons = 2 n-tiles, K=16 (zero-padded)
    #pragma unroll
    for (int nt = 0; nt < 2; ++nt){
        float x[8];
        #pragma unroll
        for (int e = 0; e < 8; ++e){
            int k = 8*g + e;
            x[e] = (k < 16) ? tW1[k*32 + nt*16 + c] : 0.f;
        }
        split8(x, Bth[nt], Btl[nt]);
    }
    float ib1c[4], tb1c[2];
    #pragma unroll
    for (int nt = 0; nt < 4; ++nt) ib1c[nt] = ib1[nt*16 + c];
    #pragma unroll
    for (int nt = 0; nt < 2; ++nt) tb1c[nt] = tb1[nt*16 + c];

    // ---------------- Phase 1: M-tile loop (16 samples each) ----------------
    #pragma unroll 1
    for (int ms = 0; ms < 4; ++ms){
        long long m = blockBase + wv*64 + ms*16 + c;
        if (m >= B) m = B - 1;                    // clamp (phase-2 guards output)
        const float* irow = image + m*48;
        const float* trow = text  + m*16;

        short8v Aih[2], Ail[2], Ath, Atl;
        {
            float x[8];
            float4 v0 = *(const float4*)(irow + 8*g);
            float4 v1 = *(const float4*)(irow + 8*g + 4);
            x[0]=v0.x; x[1]=v0.y; x[2]=v0.z; x[3]=v0.w;
            x[4]=v1.x; x[5]=v1.y; x[6]=v1.z; x[7]=v1.w;
            split8(x, Aih[0], Ail[0]);

            float xi[8], xt[8];
            #pragma unroll
            for (int e = 0; e < 8; ++e){ xi[e] = 0.f; xt[e] = 0.f; }
            if (g < 2){
                float4 v2 = *(const float4*)(irow + 32 + 8*g);
                float4 v3 = *(const float4*)(irow + 32 + 8*g + 4);
                xi[0]=v2.x; xi[1]=v2.y; xi[2]=v2.z; xi[3]=v2.w;
                xi[4]=v3.x; xi[5]=v3.y; xi[6]=v3.z; xi[7]=v3.w;
                float4 t0 = *(const float4*)(trow + 8*g);
                float4 t1 = *(const float4*)(trow + 8*g + 4);
                xt[0]=t0.x; xt[1]=t0.y; xt[2]=t0.z; xt[3]=t0.w;
                xt[4]=t1.x; xt[5]=t1.y; xt[6]=t1.z; xt[7]=t1.w;
            }
            split8(xi, Aih[1], Ail[1]);
            split8(xt, Ath, Atl);
        }

        float po[4][4];                           // [sample r][feat o] partials
        #pragma unroll
        for (int r = 0; r < 4; ++r)
            #pragma unroll
            for (int o = 0; o < 4; ++o) po[r][o] = 0.f;

        // image: h2 = relu(x@iW1 + ib1); po += h2 @ iW2
        #pragma unroll
        for (int nt = 0; nt < 4; ++nt){
            f32x4 cc = { ib1c[nt], ib1c[nt], ib1c[nt], ib1c[nt] };
            #pragma unroll
            for (int ks = 0; ks < 2; ++ks){
                cc = __builtin_amdgcn_mfma_f32_16x16x32_bf16(Aih[ks], Bih[nt][ks], cc, 0, 0, 0);
                cc = __builtin_amdgcn_mfma_f32_16x16x32_bf16(Aih[ks], Bil[nt][ks], cc, 0, 0, 0);
                cc = __builtin_amdgcn_mfma_f32_16x16x32_bf16(Ail[ks], Bih[nt][ks], cc, 0, 0, 0);
            }
            const float4 w2 = *(const float4*)(iW2 + (nt*16 + c)*4);
            #pragma unroll
            for (int r = 0; r < 4; ++r){
                float h = fmaxf(cc[r], 0.f);
                po[r][0] = fmaf(h, w2.x, po[r][0]);
                po[r][1] = fmaf(h, w2.y, po[r][1]);
                po[r][2] = fmaf(h, w2.z, po[r][2]);
                po[r][3] = fmaf(h, w2.w, po[r][3]);
            }
        }
        // text: h1 = relu(x@tW1 + tb1); po += h1 @ tW2
        #pragma unroll
        for (int nt = 0; nt < 2; ++nt){
            f32x4 cc = { tb1c[nt], tb1c[nt], tb1c[nt], tb1c[nt] };
            cc = __builtin_amdgcn_mfma_f32_16x16x32_bf16(Ath, Bth[nt], cc, 0, 0, 0);
            cc = __builtin_amdgcn_mfma_f32_16x16x32_bf16(Ath, Btl[nt], cc, 0, 0, 0);
            cc = __builtin_amdgcn_mfma_f32_16x16x32_bf16(Atl, Bth[nt], cc, 0, 0, 0);
            const float4 w2 = *(const float4*)(tW2 + (nt*16 + c)*4);
            #pragma unroll
            for (int r = 0; r < 4; ++r){
                float h = fmaxf(cc[r], 0.f);
                po[r][0] = fmaf(h, w2.x, po[r][0]);
                po[r][1] = fmaf(h, w2.y, po[r][1]);
                po[r][2] = fmaf(h, w2.z, po[r][2]);
                po[r][3] = fmaf(h, w2.w, po[r][3]);
            }
        }

        // reduce over the 16-lane c dimension (N was distributed over lanes)
        #pragma unroll
        for (int r = 0; r < 4; ++r)
            #pragma unroll
            for (int o = 0; o < 4; ++o){
                float v = po[r][o];
                v += __shfl_xor(v, 1);
                v += __shfl_xor(v, 2);
                v += __shfl_xor(v, 4);
                v += __shfl_xor(v, 8);
                po[r][o] = v;
            }

        // D row (sample within tile) = 4*g + r ; lanes c<4 write r=c
        if (c < 4){
            float4 v;
            if      (c == 0) v = make_float4(po[0][0], po[0][1], po[0][2], po[0][3]);
            else if (c == 1) v = make_float4(po[1][0], po[1][1], po[1][2], po[1][3]);
            else if (c == 2) v = make_float4(po[2][0], po[2][1], po[2][2], po[2][3]);
            else             v = make_float4(po[3][0], po[3][1], po[3][2], po[3][3]);
            feats[wv*64 + ms*16 + 4*g + c] = v;
        }
    }

    __syncthreads();

    // ---------------- Phase 2: per-thread quantum form + head ---------------
    long long samp = blockBase + t;
    if (samp < B){
        float4 f4 = feats[t];
        float acc[4];
        acc[0] = tb2[0] + ib2[0] + f4.x;
        acc[1] = tb2[1] + ib2[1] + f4.y;
        acc[2] = tb2[2] + ib2[2] + f4.z;
        acc[3] = tb2[3] + ib2[3] + f4.w;

        float cth[4], sth[4];
        #pragma unroll
        for (int i = 0; i < 4; ++i){
            float f = acc[i] * 0.25f;
            __sincosf(f, &sth[i], &cth[i]);
        }
        float p01[4] = { cth[0]*cth[1], cth[0]*sth[1], sth[0]*cth[1], sth[0]*sth[1] };
        float p23[4] = { cth[2]*cth[3], cth[2]*sth[3], sth[2]*cth[3], sth[2]*sth[3] };
        float psi[16];
        #pragma unroll
        for (int x = 0; x < 4; ++x)
            #pragma unroll
            for (int y = 0; y < 4; ++y)
                psi[x*4+y] = p01[x] * p23[y];

        float q = 0.f;
        #pragma unroll
        for (int j = 0; j < 16; ++j){
            float row = 0.f;
            #pragma unroll
            for (int k = 0; k < 16; ++k) row = fmaf(A[j*16+k], psi[k], row);
            q = fmaf(psi[j], row, q);
        }

        float o0 = cb2[0], o1 = cb2[1];
        #pragma unroll
        for (int j = 0; j < 16; ++j){
            float h = fmaxf(fmaf(q, cW1[j], cb1[j]), 0.f);
            o0 = fmaf(h, cW2[j*2+0], o0);
            o1 = fmaf(h, cW2[j*2+1], o1);
        }
        float2* o2 = (float2*)out;
        o2[samp] = make_float2(o0, o1);
    }
}

extern "C" void kernel_launch(void* const* d_in, const int* in_sizes, int n_in,
                              void* d_out, int out_size, void* d_ws, size_t ws_size,
                              hipStream_t stream)
{
    const float* text  = (const float*)d_in[0];
    const float* image = (const float*)d_in[1];
    const float* tW1   = (const float*)d_in[2];
    const float* tb1   = (const float*)d_in[3];
    const float* tW2   = (const float*)d_in[4];
    const float* tb2   = (const float*)d_in[5];
    const float* iW1   = (const float*)d_in[6];
    const float* ib1   = (const float*)d_in[7];
    const float* iW2   = (const float*)d_in[8];
    const float* ib2   = (const float*)d_in[9];
    const float* qw    = (const float*)d_in[10];
    const float* cW1   = (const float*)d_in[11];
    const float* cb1   = (const float*)d_in[12];
    const float* cW2   = (const float*)d_in[13];
    const float* cb2   = (const float*)d_in[14];

    float* A = (float*)d_ws;          // 256 floats
    int B = in_sizes[0] / 16;

    qnn_precompute_A<<<1, 256, 0, stream>>>(qw, A);

    int block = 256;
    int grid = (B + block - 1) / block;
    qnn_main<<<grid, block, 0, stream>>>(
        text, image, tW1, tb1, tW2, tb2, iW1, ib1, iW2, ib2,
        A, cW1, cb1, cW2, cb2, (float*)d_out, B);
}

// Round 3
// 286.918 us; speedup vs baseline: 1.0033x; 1.0033x over previous
//
#include <hip/hip_runtime.h>
#include <math.h>

#define NQ 4
#define NL 2

typedef __attribute__((ext_vector_type(8))) short short8v;  // 8 x bf16 (4 VGPRs)
typedef __attribute__((ext_vector_type(4))) float f32x4;

__device__ inline unsigned short f2bf(float x){
    unsigned u = __float_as_uint(x);
    u += 0x7FFFu + ((u >> 16) & 1u);          // RNE
    return (unsigned short)(u >> 16);
}
__device__ inline float bf2f(unsigned short h){
    return __uint_as_float(((unsigned)h) << 16);
}
// split x into hi (bf16) + lo (bf16 of residual); 3-term MFMA keeps ~fp32 accuracy
__device__ inline void split8(const float* x, short8v& hi, short8v& lo){
    #pragma unroll
    for (int e = 0; e < 8; ++e){
        unsigned short h = f2bf(x[e]);
        hi[e] = (short)h;
        lo[e] = (short)f2bf(x[e] - bf2f(h));
    }
}

// ---------------------------------------------------------------------------
// Kernel 1: precompute A = Re(M^dagger D M)  (unchanged)
// ---------------------------------------------------------------------------
__global__ void qnn_precompute_A(const float* __restrict__ qw, float* __restrict__ A)
{
    __shared__ float Mre[16][16];
    __shared__ float Mim[16][16];
    int t = threadIdx.x;
    if (t < 16) {
        int j = t;
        float re[16], im[16];
        for (int b = 0; b < 16; ++b) { re[b] = (b == j) ? 1.f : 0.f; im[b] = 0.f; }
        for (int l = 0; l < NL; ++l) {
            for (int i = 0; i < NQ; ++i) {
                float phi   = qw[(l*NQ + i)*3 + 0];
                float theta = qw[(l*NQ + i)*3 + 1];
                float omega = qw[(l*NQ + i)*3 + 2];
                float ct, st; sincosf(0.5f*theta, &st, &ct);
                float ap = 0.5f*(phi + omega);
                float am = 0.5f*(phi - omega);
                float cap, sap, cam, sam;
                sincosf(ap, &sap, &cap);
                sincosf(am, &sam, &cam);
                float u00r =  cap*ct, u00i = -sap*ct;
                float u01r = -cam*st, u01i = -sam*st;
                float u10r =  cam*st, u10i = -sam*st;
                float u11r =  cap*ct, u11i =  sap*ct;
                int mask = 1 << (3 - i);
                for (int b = 0; b < 16; ++b) {
                    if (b & mask) continue;
                    int b1 = b | mask;
                    float a0r = re[b],  a0i = im[b];
                    float a1r = re[b1], a1i = im[b1];
                    re[b]  = u00r*a0r - u00i*a0i + u01r*a1r - u01i*a1i;
                    im[b]  = u00r*a0i + u00i*a0r + u01r*a1i + u01i*a1r;
                    re[b1] = u10r*a0r - u10i*a0i + u11r*a1r - u11i*a1i;
                    im[b1] = u10r*a0i + u10i*a0r + u11r*a1i + u11i*a1r;
                }
            }
            for (int b = 0; b < 16; ++b) {
                float sgn = 1.f;
                if ((b & 0xC) == 0xC) sgn = -sgn;
                if ((b & 0x6) == 0x6) sgn = -sgn;
                if ((b & 0x3) == 0x3) sgn = -sgn;
                re[b] *= sgn; im[b] *= sgn;
            }
        }
        for (int b = 0; b < 16; ++b) { Mre[j][b] = re[b]; Mim[j][b] = im[b]; }
    }
    __syncthreads();
    {
        int j = t >> 4, k = t & 15;
        float s = 0.f;
        #pragma unroll
        for (int b = 0; b < 16; ++b) {
            float sg = (b & 8) ? -1.f : 1.f;
            s += sg * (Mre[j][b]*Mre[k][b] + Mim[j][b]*Mim[k][b]);
        }
        A[j*16 + k] = s;
    }
}

// ---------------------------------------------------------------------------
// helpers for kernel 2
// ---------------------------------------------------------------------------
__device__ inline void po_update(float (&po)[4][4], const f32x4& cc, const float4& w2){
    #pragma unroll
    for (int r = 0; r < 4; ++r){
        float h = fmaxf(cc[r], 0.f);
        po[r][0] = fmaf(h, w2.x, po[r][0]);
        po[r][1] = fmaf(h, w2.y, po[r][1]);
        po[r][2] = fmaf(h, w2.z, po[r][2]);
        po[r][3] = fmaf(h, w2.w, po[r][3]);
    }
}
__device__ inline void reduce_po(float (&po)[4][4]){
    #pragma unroll
    for (int r = 0; r < 4; ++r)
        #pragma unroll
        for (int o = 0; o < 4; ++o){
            float v = po[r][o];
            v += __shfl_xor(v, 1);
            v += __shfl_xor(v, 2);
            v += __shfl_xor(v, 4);
            v += __shfl_xor(v, 8);
            po[r][o] = v;
        }
}
__device__ inline float4 pick_row(const float (&po)[4][4], int c){
    float4 v;
    if      (c == 0) v = make_float4(po[0][0], po[0][1], po[0][2], po[0][3]);
    else if (c == 1) v = make_float4(po[1][0], po[1][1], po[1][2], po[1][3]);
    else if (c == 2) v = make_float4(po[2][0], po[2][1], po[2][2], po[2][3]);
    else             v = make_float4(po[3][0], po[3][1], po[3][2], po[3][3]);
    return v;
}
// image A-frags: K=48 zero-padded to 64 (2 k-steps); k-slot map k = ks*32+8*g+e
__device__ inline void build_imgA(const float* irow, int g,
                                  short8v& Aih0, short8v& Ail0,
                                  short8v& Aih1, short8v& Ail1){
    float x[8];
    float4 v0 = *(const float4*)(irow + 8*g);
    float4 v1 = *(const float4*)(irow + 8*g + 4);
    x[0]=v0.x; x[1]=v0.y; x[2]=v0.z; x[3]=v0.w;
    x[4]=v1.x; x[5]=v1.y; x[6]=v1.z; x[7]=v1.w;
    split8(x, Aih0, Ail0);
    float xi[8];
    #pragma unroll
    for (int e = 0; e < 8; ++e) xi[e] = 0.f;
    if (g < 2){
        float4 v2 = *(const float4*)(irow + 32 + 8*g);
        float4 v3 = *(const float4*)(irow + 32 + 8*g + 4);
        xi[0]=v2.x; xi[1]=v2.y; xi[2]=v2.z; xi[3]=v2.w;
        xi[4]=v3.x; xi[5]=v3.y; xi[6]=v3.z; xi[7]=v3.w;
    }
    split8(xi, Aih1, Ail1);
}
// text A-frags: K=16 zero-padded to 32
__device__ inline void build_txtA(const float* trow, int g, short8v& Ath, short8v& Atl){
    float xt[8];
    #pragma unroll
    for (int e = 0; e < 8; ++e) xt[e] = 0.f;
    if (g < 2){
        float4 t0 = *(const float4*)(trow + 8*g);
        float4 t1 = *(const float4*)(trow + 8*g + 4);
        xt[0]=t0.x; xt[1]=t0.y; xt[2]=t0.z; xt[3]=t0.w;
        xt[4]=t1.x; xt[5]=t1.y; xt[6]=t1.z; xt[7]=t1.w;
    }
    split8(xt, Ath, Atl);
}

// ---------------------------------------------------------------------------
// Kernel 2: MFMA with weight CHUNKING.
// Round-2 failure: all weight fragments wave-resident at once (~180 live regs)
// -> 150B/thread scratch spill (WRITE_SIZE 80MB vs 4MB output). Fix: two
// sequential weight chunks that REUSE the same fragment registers:
//   chunk A: image neurons 0..31 (8 frags, 32 VGPR) + text (4 frags, 16 VGPR)
//   chunk B: image neurons 32..63 (8 frags, 32 VGPR)
// Per chunk, per M-tile: build A-frags, MFMA (3-term bf16 split), layer-2
// per-lane FMA with iW2/tW2 rows, shfl_xor reduce over the 16-lane neuron
// dim, accumulate partial feats into LDS. Peak live ~110 VGPR ->
// __launch_bounds__(256,4), 16 waves/CU, no spill. Image inputs re-read once
// (chunk B) -- bandwidth is at <25% of peak, latency hiding is the currency.
// Phase 2 per-thread quantum quadratic form + head unchanged (verified).
// ---------------------------------------------------------------------------
__global__ __launch_bounds__(256, 4) void qnn_main(
    const float* __restrict__ text, const float* __restrict__ image,
    const float* __restrict__ tW1, const float* __restrict__ tb1,
    const float* __restrict__ tW2, const float* __restrict__ tb2,
    const float* __restrict__ iW1, const float* __restrict__ ib1,
    const float* __restrict__ iW2, const float* __restrict__ ib2,
    const float* __restrict__ A,
    const float* __restrict__ cW1, const float* __restrict__ cb1,
    const float* __restrict__ cW2, const float* __restrict__ cb2,
    float* __restrict__ out, int B)
{
    __shared__ float4 feats[256];
    const int t    = threadIdx.x;
    const int lane = t & 63;
    const int wv   = t >> 6;
    const int g    = lane >> 4;   // k-slot group
    const int c    = lane & 15;   // A row (sample) / B col (neuron) / D col
    const long long blockBase = (long long)blockIdx.x * 256;

    // fragment registers shared by both chunks (reused)
    short8v Bh[2][2], Bl[2][2];   // [nt][ks] image-weight frags for current chunk

    // =================== chunk A: image nt 0..1  +  text ====================
    #pragma unroll
    for (int nt = 0; nt < 2; ++nt)
        #pragma unroll
        for (int ks = 0; ks < 2; ++ks){
            float x[8];
            #pragma unroll
            for (int e = 0; e < 8; ++e){
                int k = ks*32 + 8*g + e;
                x[e] = (k < 48) ? iW1[k*64 + nt*16 + c] : 0.f;
            }
            split8(x, Bh[nt][ks], Bl[nt][ks]);
        }
    short8v Bth[2], Btl[2];
    #pragma unroll
    for (int nt = 0; nt < 2; ++nt){
        float x[8];
        #pragma unroll
        for (int e = 0; e < 8; ++e){
            int k = 8*g + e;
            x[e] = (k < 16) ? tW1[k*32 + nt*16 + c] : 0.f;
        }
        split8(x, Bth[nt], Btl[nt]);
    }
    float bA0 = ib1[c], bA1 = ib1[16 + c];
    float bT0 = tb1[c], bT1 = tb1[16 + c];

    #pragma unroll 1
    for (int ms = 0; ms < 4; ++ms){
        long long m = blockBase + wv*64 + ms*16 + c;
        if (m >= B) m = B - 1;                    // clamp (phase-2 guards output)
        short8v Aih[2], Ail[2], Ath, Atl;
        build_imgA(image + m*48, g, Aih[0], Ail[0], Aih[1], Ail[1]);
        build_txtA(text  + m*16, g, Ath, Atl);

        float po[4][4];
        #pragma unroll
        for (int r = 0; r < 4; ++r)
            #pragma unroll
            for (int o = 0; o < 4; ++o) po[r][o] = 0.f;

        #pragma unroll
        for (int nt = 0; nt < 2; ++nt){
            float bb = (nt == 0) ? bA0 : bA1;
            f32x4 cc = { bb, bb, bb, bb };
            #pragma unroll
            for (int ks = 0; ks < 2; ++ks){
                cc = __builtin_amdgcn_mfma_f32_16x16x32_bf16(Aih[ks], Bh[nt][ks], cc, 0, 0, 0);
                cc = __builtin_amdgcn_mfma_f32_16x16x32_bf16(Aih[ks], Bl[nt][ks], cc, 0, 0, 0);
                cc = __builtin_amdgcn_mfma_f32_16x16x32_bf16(Ail[ks], Bh[nt][ks], cc, 0, 0, 0);
            }
            const float4 w2 = *(const float4*)(iW2 + (nt*16 + c)*4);
            po_update(po, cc, w2);
        }
        #pragma unroll
        for (int nt = 0; nt < 2; ++nt){
            float bb = (nt == 0) ? bT0 : bT1;
            f32x4 cc = { bb, bb, bb, bb };
            cc = __builtin_amdgcn_mfma_f32_16x16x32_bf16(Ath, Bth[nt], cc, 0, 0, 0);
            cc = __builtin_amdgcn_mfma_f32_16x16x32_bf16(Ath, Btl[nt], cc, 0, 0, 0);
            cc = __builtin_amdgcn_mfma_f32_16x16x32_bf16(Atl, Bth[nt], cc, 0, 0, 0);
            const float4 w2 = *(const float4*)(tW2 + (nt*16 + c)*4);
            po_update(po, cc, w2);
        }

        reduce_po(po);
        if (c < 4)
            feats[wv*64 + ms*16 + 4*g + c] = pick_row(po, c);   // plain store
    }

    // =================== chunk B: image nt 2..3 (reuses Bh/Bl) ==============
    #pragma unroll
    for (int nt = 0; nt < 2; ++nt)
        #pragma unroll
        for (int ks = 0; ks < 2; ++ks){
            float x[8];
            #pragma unroll
            for (int e = 0; e < 8; ++e){
                int k = ks*32 + 8*g + e;
                x[e] = (k < 48) ? iW1[k*64 + (nt + 2)*16 + c] : 0.f;
            }
            split8(x, Bh[nt][ks], Bl[nt][ks]);
        }
    bA0 = ib1[32 + c]; bA1 = ib1[48 + c];

    #pragma unroll 1
    for (int ms = 0; ms < 4; ++ms){
        long long m = blockBase + wv*64 + ms*16 + c;
        if (m >= B) m = B - 1;
        short8v Aih[2], Ail[2];
        build_imgA(image + m*48, g, Aih[0], Ail[0], Aih[1], Ail[1]);

        float po[4][4];
        #pragma unroll
        for (int r = 0; r < 4; ++r)
            #pragma unroll
            for (int o = 0; o < 4; ++o) po[r][o] = 0.f;

        #pragma unroll
        for (int nt = 0; nt < 2; ++nt){
            float bb = (nt == 0) ? bA0 : bA1;
            f32x4 cc = { bb, bb, bb, bb };
            #pragma unroll
            for (int ks = 0; ks < 2; ++ks){
                cc = __builtin_amdgcn_mfma_f32_16x16x32_bf16(Aih[ks], Bh[nt][ks], cc, 0, 0, 0);
                cc = __builtin_amdgcn_mfma_f32_16x16x32_bf16(Aih[ks], Bl[nt][ks], cc, 0, 0, 0);
                cc = __builtin_amdgcn_mfma_f32_16x16x32_bf16(Ail[ks], Bh[nt][ks], cc, 0, 0, 0);
            }
            const float4 w2 = *(const float4*)(iW2 + ((nt + 2)*16 + c)*4);
            po_update(po, cc, w2);
        }

        reduce_po(po);
        if (c < 4){
            int slot = wv*64 + ms*16 + 4*g + c;
            float4 add = pick_row(po, c);
            float4 old = feats[slot];
            feats[slot] = make_float4(old.x + add.x, old.y + add.y,
                                      old.z + add.z, old.w + add.w);
        }
    }

    __syncthreads();

    // ---------------- Phase 2: per-thread quantum form + head ---------------
    long long samp = blockBase + t;
    if (samp < B){
        float4 f4 = feats[t];
        float acc[4];
        acc[0] = tb2[0] + ib2[0] + f4.x;
        acc[1] = tb2[1] + ib2[1] + f4.y;
        acc[2] = tb2[2] + ib2[2] + f4.z;
        acc[3] = tb2[3] + ib2[3] + f4.w;

        float cth[4], sth[4];
        #pragma unroll
        for (int i = 0; i < 4; ++i){
            float f = acc[i] * 0.25f;
            __sincosf(f, &sth[i], &cth[i]);
        }
        float p01[4] = { cth[0]*cth[1], cth[0]*sth[1], sth[0]*cth[1], sth[0]*sth[1] };
        float p23[4] = { cth[2]*cth[3], cth[2]*sth[3], sth[2]*cth[3], sth[2]*sth[3] };
        float psi[16];
        #pragma unroll
        for (int x = 0; x < 4; ++x)
            #pragma unroll
            for (int y = 0; y < 4; ++y)
                psi[x*4+y] = p01[x] * p23[y];

        float q = 0.f;
        #pragma unroll
        for (int j = 0; j < 16; ++j){
            float row = 0.f;
            #pragma unroll
            for (int k = 0; k < 16; ++k) row = fmaf(A[j*16+k], psi[k], row);
            q = fmaf(psi[j], row, q);
        }

        float o0 = cb2[0], o1 = cb2[1];
        #pragma unroll
        for (int j = 0; j < 16; ++j){
            float h = fmaxf(fmaf(q, cW1[j], cb1[j]), 0.f);
            o0 = fmaf(h, cW2[j*2+0], o0);
            o1 = fmaf(h, cW2[j*2+1], o1);
        }
        float2* o2 = (float2*)out;
        o2[samp] = make_float2(o0, o1);
    }
}

extern "C" void kernel_launch(void* const* d_in, const int* in_sizes, int n_in,
                              void* d_out, int out_size, void* d_ws, size_t ws_size,
                              hipStream_t stream)
{
    const float* text  = (const float*)d_in[0];
    const float* image = (const float*)d_in[1];
    const float* tW1   = (const float*)d_in[2];
    const float* tb1   = (const float*)d_in[3];
    const float* tW2   = (const float*)d_in[4];
    const float* tb2   = (const float*)d_in[5];
    const float* iW1   = (const float*)d_in[6];
    const float* ib1   = (const float*)d_in[7];
    const float* iW2   = (const float*)d_in[8];
    const float* ib2   = (const float*)d_in[9];
    const float* qw    = (const float*)d_in[10];
    const float* cW1   = (const float*)d_in[11];
    const float* cb1   = (const float*)d_in[12];
    const float* cW2   = (const float*)d_in[13];
    const float* cb2   = (const float*)d_in[14];

    float* A = (float*)d_ws;          // 256 floats
    int B = in_sizes[0] / 16;

    qnn_precompute_A<<<1, 256, 0, stream>>>(qw, A);

    int block = 256;
    int grid = (B + block - 1) / block;
    qnn_main<<<grid, block, 0, stream>>>(
        text, image, tW1, tb1, tW2, tb2, iW1, ib1, iW2, ib2,
        A, cW1, cb1, cW2, cb2, (float*)d_out, B);
}